// Round 19
// baseline (158.435 us; speedup 1.0000x reference)
//
#include <hip/hip_runtime.h>

// Problem constants (fixed by reference)
#define B_ 16
#define C_ 64
#define T_ 2048
#define O_ 64
#define KNN 3
#define HSPLIT 4
#define JCH (T_ / HSPLIT)     // 512 j per (b,h) chunk
#define NJS (JCH / 32)        // 16 j-subtiles (32 rows) per chunk

typedef short short8   __attribute__((ext_vector_type(8)));   // 8 bf16
typedef float f32x4    __attribute__((ext_vector_type(4)));
typedef unsigned short ushortx4 __attribute__((ext_vector_type(4)));

// Workspace layout (float slots). Total ~18.5 MB.
#define XT_OFF 0                              // fp32 xT[b][t][c]          : B*T*64
#define XS_OFF (XT_OFF + B_ * T_ * C_)        // ushort xs[b][t][128] hi|lo
#define NSQ_OFF (XS_OFF + B_ * T_ * C_)       // fp32 nsq[b*T+t]
#define WT_OFF (NSQ_OFF + B_ * T_)            // fp32 Wt[m][o], m=k*64+c   : 192*64
#define CAND_OFF (WT_OFF + 192 * O_)          // ushort cand[B*T][16]      : 262144 f
#define JSEL_OFF (CAND_OFF + 262144)          // int jsel[1024 tiles][96]  : 98304 f

__device__ inline ushort bf16_rne(float f) {
    union { float f; unsigned u; } cv; cv.f = f;
    unsigned u = cv.u;
    u += 0x7FFF + ((u >> 16) & 1);
    return (ushort)(u >> 16);
}
__device__ inline float bf16_val(ushort h) {
    union { unsigned u; float f; } cv; cv.u = ((unsigned)h) << 16; return cv.f;
}

// ---------------------------------------------------------------------------
// Prep v3 (XCD-pinned producer, verified).
// ---------------------------------------------------------------------------
__global__ __launch_bounds__(256) void prep_kernel(const float* __restrict__ x,
                                                   const float* __restrict__ W,
                                                   float* __restrict__ ws) {
    float*  xT  = ws + XT_OFF;
    ushort* xs  = (ushort*)(ws + XS_OFF);
    float*  nsq = ws + NSQ_OFF;
    float*  Wt  = ws + WT_OFF;
    int blk = blockIdx.x;
    int tid = threadIdx.x;
    if (blk < B_ * (T_ / 64)) {
        int b  = (blk & 7) + 8 * ((blk >> 3) & 1);
        int t0 = (blk >> 4) * 64;
        __shared__ float tl[64 * 65];
        #pragma unroll
        for (int r = 0; r < 4; ++r) {
            int c  = r * 16 + (tid >> 4);
            int t4 = (tid & 15) * 4;
            float4 v = *(const float4*)(x + (size_t)(b * C_ + c) * T_ + t0 + t4);
            tl[c * 65 + t4 + 0] = v.x;
            tl[c * 65 + t4 + 1] = v.y;
            tl[c * 65 + t4 + 2] = v.z;
            tl[c * 65 + t4 + 3] = v.w;
        }
        __syncthreads();
        #pragma unroll
        for (int r = 0; r < 4; ++r) {
            int t  = r * 16 + (tid >> 4);
            int c0 = (tid & 15) * 4;
            float v0 = tl[(c0 + 0) * 65 + t];
            float v1 = tl[(c0 + 1) * 65 + t];
            float v2 = tl[(c0 + 2) * 65 + t];
            float v3 = tl[(c0 + 3) * 65 + t];
            size_t rowg = (size_t)(b * T_ + t0 + t);
            float4 xv; xv.x = v0; xv.y = v1; xv.z = v2; xv.w = v3;
            *(float4*)(xT + rowg * 64 + c0) = xv;
            ushort h0 = bf16_rne(v0), h1 = bf16_rne(v1);
            ushort h2 = bf16_rne(v2), h3 = bf16_rne(v3);
            ushortx4 hv; hv[0] = h0; hv[1] = h1; hv[2] = h2; hv[3] = h3;
            ushortx4 lv;
            lv[0] = bf16_rne(v0 - bf16_val(h0));
            lv[1] = bf16_rne(v1 - bf16_val(h1));
            lv[2] = bf16_rne(v2 - bf16_val(h2));
            lv[3] = bf16_rne(v3 - bf16_val(h3));
            *(ushortx4*)(xs + rowg * 128 + c0)      = hv;
            *(ushortx4*)(xs + rowg * 128 + 64 + c0) = lv;
        }
        if (tid < 64) {
            float s = 0.f;
            #pragma unroll
            for (int c = 0; c < 64; ++c) { float v = tl[c * 65 + tid]; s = fmaf(v, v, s); }
            nsq[b * T_ + t0 + tid] = s;
        }
    } else {
        int e = (blk - B_ * (T_ / 64)) * 256 + tid;
        if (e < O_ * C_ * KNN) {
            int o = e / (C_ * KNN);
            int c = (e / KNN) % C_;
            int k = e % KNN;
            Wt[(k * 64 + c) * O_ + o] = W[e];
        }
    }
}

// ---------------------------------------------------------------------------
// KNN screen v8: DE-STAGED. Per block the j-working set (512 rows x 128 B hi
// = 64 KB) is L2-resident on the local XCD (prep v3 pinning) and all 8 waves
// read the SAME j-rows (L1 broadcast after first touch) — LDS staging was
// pure overhead (Common-mistake #7): 16 vmcnt(0)+barrier convoys per block.
// v8: each lane loads ah0/ah1 straight from global (same pattern as the
// i-frag load), zero j-barriers, LDS = 6 KB (nsqs + epilogue fbuf).
// Same bytes, same arithmetic -> same candidates -> bitwise-same output.
// ---------------------------------------------------------------------------
__global__ __launch_bounds__(256, 8) void knn_mfma_kernel(const ushort* __restrict__ xs,
                                                          const float* __restrict__ nsq,
                                                          ushort* __restrict__ cand) {
    __shared__ float nsqs[JCH];          // 2 KB
    __shared__ float fbuf[64 * 16];      // 4 KB (epilogue merge)

    int bid = blockIdx.x;
    // XCD-pinned bijective decode over 2048: XCD = bid&7 owns batches {bid&7, bid&7+8}
    int b   = (bid & 7) + 8 * (bid >> 10);
    int h   = (bid >> 3) & 3;
    int m   = (bid >> 5) & 31;                // 32 i-tiles of 64 rows
    int i0  = m * 64;
    int tid = threadIdx.x;
    int w   = tid >> 6, l = tid & 63, lr = l & 15, lq = l >> 4;
    const ushort* xsb = xs + (size_t)b * T_ * 128;
    int jBase = h * JCH;

    if (tid < JCH / 4)
        ((float4*)nsqs)[tid] = ((const float4*)(nsq + b * T_ + jBase))[tid];

    // i-frags (hi half only): wave w owns rows i0 + w*16 + lr
    short8 bA0, bA1;
    {
        const ushort* ia = xsb + (size_t)(i0 + w * 16 + lr) * 128 + lq * 8;
        bA0 = *(const short8*)(ia + 0);  bA1 = *(const short8*)(ia + 32);
    }
    float niA = nsq[b * T_ + i0 + w * 16 + lr] + 4.0f;

    const float INF = __builtin_inff();
    float kA0 = INF, kA1 = INF, kA2 = INF, kA3 = INF;

    __syncthreads();   // nsqs visible to all waves

    // Per-lane j-row base for this lane's fragment chunks.
    const ushort* jb0 = xsb + (size_t)(jBase + lr) * 128 + lq * 8;

    #pragma unroll 2
    for (int js = 0; js < NJS; ++js) {
        #pragma unroll
        for (int tile = 0; tile < 2; ++tile) {
            const ushort* jr = jb0 + (size_t)(js * 32 + tile * 16) * 128;
            short8 ah0 = *(const short8*)(jr + 0);
            short8 ah1 = *(const short8*)(jr + 32);
            f32x4 accA = {0.f, 0.f, 0.f, 0.f};
            accA = __builtin_amdgcn_mfma_f32_16x16x32_bf16(ah0, bA0, accA, 0, 0, 0);
            accA = __builtin_amdgcn_mfma_f32_16x16x32_bf16(ah1, bA1, accA, 0, 0, 0);
            float4 nv = *(const float4*)(nsqs + js * 32 + tile * 16 + lq * 4);
            int idb = ((js * 2 + tile) << 2) | (lq << 8);   // 10-bit id base
            #define INS(K0, K1, K2, K3, sv, idv) {                                  \
                unsigned uu = (__float_as_uint(sv) & 0xFFFFFC00u) | (unsigned)(idv); \
                float kf = __uint_as_float(uu);                                      \
                float n0 = fminf(K0, kf);                                            \
                float n1 = __builtin_amdgcn_fmed3f(K0, K1, kf);                      \
                float n2 = __builtin_amdgcn_fmed3f(K1, K2, kf);                      \
                float n3 = __builtin_amdgcn_fmed3f(K2, K3, kf);                      \
                K0 = n0; K1 = n1; K2 = n2; K3 = n3; }
            {
                float s0 = fmaf(-2.f, accA[0], nv.x + niA); INS(kA0, kA1, kA2, kA3, s0, idb + 0);
                float s1 = fmaf(-2.f, accA[1], nv.y + niA); INS(kA0, kA1, kA2, kA3, s1, idb + 1);
                float s2 = fmaf(-2.f, accA[2], nv.z + niA); INS(kA0, kA1, kA2, kA3, s2, idb + 2);
                float s3 = fmaf(-2.f, accA[3], nv.w + niA); INS(kA0, kA1, kA2, kA3, s3, idb + 3);
            }
            #undef INS
        }
    }

    // Epilogue: merge 4 lq-stripes per row -> top-4 of 16, decode, write cand.
    __syncthreads();
    {
        float* pa = fbuf + (w * 16 + lr) * 16 + lq * 4;
        pa[0] = kA0; pa[1] = kA1; pa[2] = kA2; pa[3] = kA3;
    }
    __syncthreads();
    if (tid < 64) {
        const float* pr = fbuf + tid * 16;
        float m0 = INF, m1 = INF, m2 = INF, m3 = INF;
        #pragma unroll
        for (int q2 = 0; q2 < 16; ++q2) {
            float kf = pr[q2];
            float n0 = fminf(m0, kf);
            float n1 = __builtin_amdgcn_fmed3f(m0, m1, kf);
            float n2 = __builtin_amdgcn_fmed3f(m1, m2, kf);
            float n3 = __builtin_amdgcn_fmed3f(m2, m3, kf);
            m0 = n0; m1 = n1; m2 = n2; m3 = n3;
        }
        ushortx4 cv;
        #define DEC(mf, slot) { unsigned u = __float_as_uint(mf) & 1023u;            \
            cv[slot] = (ushort)(jBase + (((u >> 2) & 63u) << 4) + ((u >> 8) << 2) + (u & 3)); }
        DEC(m0, 0); DEC(m1, 1); DEC(m2, 2); DEC(m3, 3);
        #undef DEC
        int row = b * T_ + i0 + tid;
        *(ushortx4*)(cand + (size_t)row * 16 + h * 4) = cv;
    }
}

// ---------------------------------------------------------------------------
// Refine kernel (verified R18): conv phases 1a-1c, writes per-tile top-3 to
// global jsel (384 B/block). 1024 blocks, 4/CU.
// ---------------------------------------------------------------------------
__global__ __launch_bounds__(256, 4) void refine_kernel(const float* __restrict__ ws,
                                                        float* __restrict__ wsw) {
    const float*  xT   = ws + XT_OFF;
    const float*  nsq  = ws + NSQ_OFF;
    const ushort* cand = (const ushort*)(ws + CAND_OFF);
    int* jsel_g = (int*)(wsw + JSEL_OFF);

    __shared__ float sref[32 * 17];
    __shared__ int   jref[32 * 17];
    __shared__ float q_s[32 * 68];
    __shared__ int   jsel3[32 * 3];

    int bid = blockIdx.x;
    int bb  = (bid & 7) + 8 * (bid >> 9);
    int i0  = ((bid >> 3) & 63) * 32;
    int tid = threadIdx.x;
    int w = tid >> 6, l = tid & 63;
    int bT = bb * T_;

    {
        int row = tid >> 3;
        int c8  = tid & 7;
        const float4* src = (const float4*)(xT + (size_t)(bT + i0 + row) * 64 + c8 * 8);
        float4 v0 = src[0], v1 = src[1];
        *(float4*)(q_s + row * 68 + c8 * 8)     = v0;
        *(float4*)(q_s + row * 68 + c8 * 8 + 4) = v1;
    }

    const float INF = __builtin_inff();
    int cd  = l >> 2;
    int c16 = l & 3;
    int rbase = i0 + w * 8;
    int jtA[8];
    #pragma unroll
    for (int rr = 0; rr < 8; ++rr)
        jtA[rr] = cand[(size_t)(bT + rbase + rr) * 16 + cd];
    __builtin_amdgcn_sched_barrier(0);
    float nsqj[8];
    #pragma unroll
    for (int rr = 0; rr < 8; ++rr)
        nsqj[rr] = nsq[bT + jtA[rr]];

    #pragma unroll
    for (int rp = 0; rp < 2; ++rp) {
        float4 bv0[4], bv1[4], bv2[4], bv3[4];
        #pragma unroll
        for (int r4 = 0; r4 < 4; ++r4) {
            const float4* bp = (const float4*)(xT + (size_t)(bT + jtA[rp * 4 + r4]) * 64 + c16 * 16);
            bv0[r4] = bp[0]; bv1[r4] = bp[1]; bv2[r4] = bp[2]; bv3[r4] = bp[3];
        }
        __builtin_amdgcn_sched_barrier(0);
        #pragma unroll
        for (int r4 = 0; r4 < 4; ++r4) {
            int rl = w * 8 + rp * 4 + r4;
            int jt = jtA[rp * 4 + r4];
            const float4* ap = (const float4*)(q_s + rl * 68 + c16 * 16);
            float4 a0 = ap[0], a1 = ap[1], a2 = ap[2], a3 = ap[3];
            float4 b0 = bv0[r4], b1 = bv1[r4], b2 = bv2[r4], b3 = bv3[r4];
            float p0 = fmaf(b0.w, a0.w, fmaf(b0.z, a0.z, fmaf(b0.y, a0.y, b0.x * a0.x)));
            float p1 = fmaf(b1.w, a1.w, fmaf(b1.z, a1.z, fmaf(b1.y, a1.y, b1.x * a1.x)));
            float p2 = fmaf(b2.w, a2.w, fmaf(b2.z, a2.z, fmaf(b2.y, a2.y, b2.x * a2.x)));
            float p3 = fmaf(b3.w, a3.w, fmaf(b3.z, a3.z, fmaf(b3.y, a3.y, b3.x * a3.x)));
            float p = (p0 + p1) + (p2 + p3);
            p += __shfl_xor(p, 1, 64);
            p += __shfl_xor(p, 2, 64);
            float s = nsqj[rp * 4 + r4] - 2.f * p;
            if (c16 == 0) { sref[rl * 17 + cd] = s; jref[rl * 17 + cd] = jt; }
        }
    }
    __syncthreads();

    if (tid < 32) {
        const float* sp = sref + tid * 17;
        const int*   jp = jref + tid * 17;
        float D0 = INF, D1 = INF, D2 = INF;
        int   I0 = 0x7FFFFFFF, I1 = 0x7FFFFFFF, I2 = 0x7FFFFFFF;
        #pragma unroll
        for (int t = 0; t < 16; ++t) {
            float s  = sp[t];
            int   jt = jp[t];
            bool lt2 = (s < D2) || (s == D2 && jt < I2);
            bool lt1 = (s < D1) || (s == D1 && jt < I1);
            bool lt0 = (s < D0) || (s == D0 && jt < I0);
            float nD2 = lt1 ? D1 : (lt2 ? s : D2); int nI2 = lt1 ? I1 : (lt2 ? jt : I2);
            float nD1 = lt0 ? D0 : (lt1 ? s : D1); int nI1 = lt0 ? I0 : (lt1 ? jt : I1);
            D2 = nD2; I2 = nI2; D1 = nD1; I1 = nI1;
            D0 = lt0 ? s : D0; I0 = lt0 ? jt : I0;
        }
        jsel3[tid * 3 + 0] = I0; jsel3[tid * 3 + 1] = I1; jsel3[tid * 3 + 2] = I2;
    }
    __syncthreads();
    if (tid < 96) jsel_g[(size_t)bid * 96 + tid] = jsel3[tid];
}

// ---------------------------------------------------------------------------
// Conv kernel with Wt staged in LDS (verified R18). 1024 blocks, 2/CU.
// ---------------------------------------------------------------------------
__global__ __launch_bounds__(256, 2) void conv_w_kernel(const float* __restrict__ ws,
                                                        const float* __restrict__ bias,
                                                        float* __restrict__ out) {
    const float*  xT   = ws + XT_OFF;
    const float*  Wt   = ws + WT_OFF;
    const int* jsel_g  = (const int*)(ws + JSEL_OFF);

    __shared__ __align__(16) float wt_s[192 * 64];   // 48 KB
    __shared__ float g_s[192 * 32];                  // 24 KB

    int bid = blockIdx.x;
    int bb  = (bid & 7) + 8 * (bid >> 9);
    int i0  = ((bid >> 3) & 63) * 32;
    int tid = threadIdx.x;
    int bT = bb * T_;

    // Stage Wt -> LDS: 12 rounds x 256 threads x 16 B (linear, coalesced).
    #pragma unroll
    for (int r = 0; r < 12; ++r) {
        const float* gp = Wt + (r * 256 + tid) * 4;
        __builtin_amdgcn_global_load_lds(
            (const __attribute__((address_space(1))) void*)gp,
            (__attribute__((address_space(3))) void*)(wt_s + (r * 256 + tid) * 4),
            16, 0, 0);
    }

    // Phase 2 gather (independent of Wt; overlaps the DMA latency).
    if (tid < 192) {
        int k    = tid >> 6;
        int r6   = tid & 63;
        int ip   = r6 >> 1;
        int half = r6 & 1;
        int j = jsel_g[(size_t)bid * 96 + ip * 3 + k];
        const float4* src = (const float4*)(xT + (size_t)(bT + j) * 64 + half * 32);
        #pragma unroll
        for (int q = 0; q < 8; ++q) {
            float4 v = src[q];
            int mm = k * 64 + (half * 8 + q) * 4;
            g_s[(mm + 0) * 32 + ip] = v.x;
            g_s[(mm + 1) * 32 + ip] = v.y;
            g_s[(mm + 2) * 32 + ip] = v.z;
            g_s[(mm + 3) * 32 + ip] = v.w;
        }
    }
    __syncthreads();   // drains Wt DMA (vmcnt) + g_s writes (lgkmcnt)

    // Phase 3: conv from LDS. Per-(o,i) fmaf chain identical to R6/R15.
    int oq = tid >> 4;
    int iq = tid & 15;
    float a0x = 0.f, a0y = 0.f, a1x = 0.f, a1y = 0.f;
    float a2x = 0.f, a2y = 0.f, a3x = 0.f, a3y = 0.f;
    #pragma unroll 4
    for (int mm = 0; mm < 192; ++mm) {
        float4 wv = *(const float4*)(wt_s + mm * 64 + oq * 4);
        float2 gv = *(const float2*)(g_s + mm * 32 + iq * 2);
        a0x = fmaf(wv.x, gv.x, a0x); a0y = fmaf(wv.x, gv.y, a0y);
        a1x = fmaf(wv.y, gv.x, a1x); a1y = fmaf(wv.y, gv.y, a1y);
        a2x = fmaf(wv.z, gv.x, a2x); a2y = fmaf(wv.z, gv.y, a2y);
        a3x = fmaf(wv.w, gv.x, a3x); a3y = fmaf(wv.w, gv.y, a3y);
    }
    int o0 = oq * 4;
    float b0 = bias[o0], b1 = bias[o0 + 1], b2 = bias[o0 + 2], b3 = bias[o0 + 3];
    float2 r0; r0.x = a0x + b0; r0.y = a0y + b0;
    float2 r1; r1.x = a1x + b1; r1.y = a1y + b1;
    float2 r2; r2.x = a2x + b2; r2.y = a2y + b2;
    float2 r3; r3.x = a3x + b3; r3.y = a3y + b3;
    size_t ob = (size_t)(bb * O_ + o0) * T_ + i0 + iq * 2;
    *(float2*)(out + ob)          = r0;
    *(float2*)(out + ob + T_)     = r1;
    *(float2*)(out + ob + 2 * T_) = r2;
    *(float2*)(out + ob + 3 * T_) = r3;
}

// ---------------------------------------------------------------------------
extern "C" void kernel_launch(void* const* d_in, const int* in_sizes, int n_in,
                              void* d_out, int out_size, void* d_ws, size_t ws_size,
                              hipStream_t stream) {
    const float* x    = (const float*)d_in[0];
    const float* W    = (const float*)d_in[1];
    const float* bias = (const float*)d_in[2];
    float* out = (float*)d_out;
    float* ws  = (float*)d_ws;
    // requires ~18.5 MB workspace

    prep_kernel<<<B_ * (T_ / 64) + 48, 256, 0, stream>>>(x, W, ws);
    knn_mfma_kernel<<<2048, 256, 0, stream>>>(
        (const ushort*)(ws + XS_OFF), ws + NSQ_OFF, (ushort*)(ws + CAND_OFF));
    refine_kernel<<<B_ * 64, 256, 0, stream>>>(ws, ws);
    conv_w_kernel<<<B_ * 64, 256, 0, stream>>>(ws, bias, out);
}

// Round 21
// 122.693 us; speedup vs baseline: 1.2913x; 1.2913x over previous
//
#include <hip/hip_runtime.h>

// Problem constants (fixed by reference)
#define B_ 16
#define C_ 64
#define T_ 2048
#define O_ 64
#define KNN 3
#define HSPLIT 4
#define JCH (T_ / HSPLIT)     // 512 j per (b,h) chunk
#define NJP (JCH / 64)        // 8 staged 64-row j-stages per chunk

typedef short short8   __attribute__((ext_vector_type(8)));   // 8 bf16
typedef float f32x4    __attribute__((ext_vector_type(4)));
typedef unsigned short ushortx4 __attribute__((ext_vector_type(4)));

// Workspace layout (float slots). Total ~18.5 MB.
#define XT_OFF 0                              // fp32 xT[b][t][c]          : B*T*64
#define XS_OFF (XT_OFF + B_ * T_ * C_)        // ushort xs[b][t][128] hi|lo
#define NSQ_OFF (XS_OFF + B_ * T_ * C_)       // fp32 nsq[b*T+t]
#define WT_OFF (NSQ_OFF + B_ * T_)            // fp32 Wt[m][o], m=k*64+c   : 192*64
#define CAND_OFF (WT_OFF + 192 * O_)          // ushort cand[B*T][16]      : 262144 f
#define JSEL_OFF (CAND_OFF + 262144)          // int jsel[1024 tiles][96]  : 98304 f

__device__ inline ushort bf16_rne(float f) {
    union { float f; unsigned u; } cv; cv.f = f;
    unsigned u = cv.u;
    u += 0x7FFF + ((u >> 16) & 1);
    return (ushort)(u >> 16);
}
__device__ inline float bf16_val(ushort h) {
    union { unsigned u; float f; } cv; cv.u = ((unsigned)h) << 16; return cv.f;
}

// ---------------------------------------------------------------------------
// Prep v3 (XCD-pinned producer, verified).
// ---------------------------------------------------------------------------
__global__ __launch_bounds__(256) void prep_kernel(const float* __restrict__ x,
                                                   const float* __restrict__ W,
                                                   float* __restrict__ ws) {
    float*  xT  = ws + XT_OFF;
    ushort* xs  = (ushort*)(ws + XS_OFF);
    float*  nsq = ws + NSQ_OFF;
    float*  Wt  = ws + WT_OFF;
    int blk = blockIdx.x;
    int tid = threadIdx.x;
    if (blk < B_ * (T_ / 64)) {
        int b  = (blk & 7) + 8 * ((blk >> 3) & 1);
        int t0 = (blk >> 4) * 64;
        __shared__ float tl[64 * 65];
        #pragma unroll
        for (int r = 0; r < 4; ++r) {
            int c  = r * 16 + (tid >> 4);
            int t4 = (tid & 15) * 4;
            float4 v = *(const float4*)(x + (size_t)(b * C_ + c) * T_ + t0 + t4);
            tl[c * 65 + t4 + 0] = v.x;
            tl[c * 65 + t4 + 1] = v.y;
            tl[c * 65 + t4 + 2] = v.z;
            tl[c * 65 + t4 + 3] = v.w;
        }
        __syncthreads();
        #pragma unroll
        for (int r = 0; r < 4; ++r) {
            int t  = r * 16 + (tid >> 4);
            int c0 = (tid & 15) * 4;
            float v0 = tl[(c0 + 0) * 65 + t];
            float v1 = tl[(c0 + 1) * 65 + t];
            float v2 = tl[(c0 + 2) * 65 + t];
            float v3 = tl[(c0 + 3) * 65 + t];
            size_t rowg = (size_t)(b * T_ + t0 + t);
            float4 xv; xv.x = v0; xv.y = v1; xv.z = v2; xv.w = v3;
            *(float4*)(xT + rowg * 64 + c0) = xv;
            ushort h0 = bf16_rne(v0), h1 = bf16_rne(v1);
            ushort h2 = bf16_rne(v2), h3 = bf16_rne(v3);
            ushortx4 hv; hv[0] = h0; hv[1] = h1; hv[2] = h2; hv[3] = h3;
            ushortx4 lv;
            lv[0] = bf16_rne(v0 - bf16_val(h0));
            lv[1] = bf16_rne(v1 - bf16_val(h1));
            lv[2] = bf16_rne(v2 - bf16_val(h2));
            lv[3] = bf16_rne(v3 - bf16_val(h3));
            *(ushortx4*)(xs + rowg * 128 + c0)      = hv;
            *(ushortx4*)(xs + rowg * 128 + 64 + c0) = lv;
        }
        if (tid < 64) {
            float s = 0.f;
            #pragma unroll
            for (int c = 0; c < 64; ++c) { float v = tl[c * 65 + tid]; s = fmaf(v, v, s); }
            nsq[b * T_ + t0 + tid] = s;
        }
    } else {
        int e = (blk - B_ * (T_ / 64)) * 256 + tid;
        if (e < O_ * C_ * KNN) {
            int o = e / (C_ * KNN);
            int c = (e / KNN) % C_;
            int k = e % KNN;
            Wt[(k * 64 + c) * O_ + o] = W[e];
        }
    }
}

// ---------------------------------------------------------------------------
// KNN screen v9 = v7 (verified, ~28us) with 64-row stages: 2 j-subtiles per
// buffer (2 DMA issues/thread/stage) -> 8 vmcnt+barrier convoys instead of
// 16. Swizzle unchanged (row&7 invariant: subtiles are 32 rows). id encoding
// unchanged (global 16-row tile index jsp*4+tile spans 0..31). LDS 18 KB.
// R18 lesson: do NOT de-stage — the DMA amortizes j-row loads across all 8
// waves (v8: VGPR 16, 64.5us latency convoy).
// ---------------------------------------------------------------------------
__global__ __launch_bounds__(256, 8) void knn_mfma_kernel(const ushort* __restrict__ xs,
                                                          const float* __restrict__ nsq,
                                                          ushort* __restrict__ cand) {
    __shared__ __align__(16) ushort jbuf[2][64 * 64];    // 2 x 8 KB, XOR-swizzled
    __shared__ float nsqs[JCH];                          // 2 KB

    int bid = blockIdx.x;
    // XCD-pinned bijective decode over 2048: XCD = bid&7 owns batches {bid&7, bid&7+8}
    int b   = (bid & 7) + 8 * (bid >> 10);
    int h   = (bid >> 3) & 3;
    int m   = (bid >> 5) & 31;                // 32 i-tiles of 64 rows
    int i0  = m * 64;
    int tid = threadIdx.x;
    int w   = tid >> 6, l = tid & 63, lr = l & 15, lq = l >> 4;
    const ushort* xsb = xs + (size_t)b * T_ * 128;
    int jBase = h * JCH;

    if (tid < JCH / 4)
        ((float4*)nsqs)[tid] = ((const float4*)(nsq + b * T_ + jBase))[tid];

    // i-frags (hi half only): wave w owns rows i0 + w*16 + lr
    short8 bA0, bA1;
    {
        const ushort* ia = xsb + (size_t)(i0 + w * 16 + lr) * 128 + lq * 8;
        bA0 = *(const short8*)(ia + 0);  bA1 = *(const short8*)(ia + 32);
    }
    float niA = nsq[b * T_ + i0 + w * 16 + lr] + 4.0f;

    const float INF = __builtin_inff();
    float kA0 = INF, kA1 = INF, kA2 = INF, kA3 = INF;

    // DMA: 2 x 16B loads/thread/stage (one per 32-row subtile). Lane covers
    // (rloc = w*8 + l>>3, phys chunk pc = l&7); global chunk gc = pc ^
    // (rloc&7). LDS dest linear within subtile.
    int rloc_d = w * 8 + (l >> 3);
    int pc_d   = l & 7;
    int gc_d   = pc_d ^ (rloc_d & 7);
    #define ISSUE_DMA(jspv, bufv) {                                              \
        _Pragma("unroll")                                                        \
        for (int p = 0; p < 2; ++p) {                                            \
            const ushort* gp = xsb + (size_t)(jBase + (jspv) * 64 + p * 32 + rloc_d) * 128 + gc_d * 8; \
            __builtin_amdgcn_global_load_lds(                                    \
                (const __attribute__((address_space(1))) void*)gp,               \
                (__attribute__((address_space(3))) void*)(jbuf[bufv] + (p * 32 + rloc_d) * 64 + pc_d * 8), \
                16, 0, 0);                                                       \
        } }

    // Drain the nsqs ds_write so it is visible to all waves after barrier 0.
    asm volatile("s_waitcnt lgkmcnt(0)" ::: "memory");

    // Prologue: first stage in flight.
    ISSUE_DMA(0, 0);

    #pragma unroll 1
    for (int jsp = 0; jsp < NJP; ++jsp) {
        asm volatile("s_waitcnt vmcnt(0)" ::: "memory");
        __builtin_amdgcn_s_barrier();            // raw barrier: jsp-1 compute done everywhere
        asm volatile("" ::: "memory");
        __builtin_amdgcn_sched_barrier(0);
        if (jsp + 1 < NJP) ISSUE_DMA(jsp + 1, (jsp + 1) & 1);
        const char* jb8 = (const char*)jbuf[jsp & 1];
        #pragma unroll
        for (int tile = 0; tile < 4; ++tile) {
            int r = tile * 16 + lr;               // 0..63 within stage
            const char* rowp = jb8 + r * 128;
            short8 ah0 = *(const short8*)(rowp + (((lq)     ^ (r & 7)) << 4));
            short8 ah1 = *(const short8*)(rowp + (((4 + lq) ^ (r & 7)) << 4));
            f32x4 accA = {0.f, 0.f, 0.f, 0.f};
            accA = __builtin_amdgcn_mfma_f32_16x16x32_bf16(ah0, bA0, accA, 0, 0, 0);
            accA = __builtin_amdgcn_mfma_f32_16x16x32_bf16(ah1, bA1, accA, 0, 0, 0);
            float4 nv = *(const float4*)(nsqs + jsp * 64 + tile * 16 + lq * 4);
            int idb = ((jsp * 4 + tile) << 2) | (lq << 8);   // 10-bit id base
            #define INS(K0, K1, K2, K3, sv, idv) {                                  \
                unsigned uu = (__float_as_uint(sv) & 0xFFFFFC00u) | (unsigned)(idv); \
                float kf = __uint_as_float(uu);                                      \
                float n0 = fminf(K0, kf);                                            \
                float n1 = __builtin_amdgcn_fmed3f(K0, K1, kf);                      \
                float n2 = __builtin_amdgcn_fmed3f(K1, K2, kf);                      \
                float n3 = __builtin_amdgcn_fmed3f(K2, K3, kf);                      \
                K0 = n0; K1 = n1; K2 = n2; K3 = n3; }
            {
                float s0 = fmaf(-2.f, accA[0], nv.x + niA); INS(kA0, kA1, kA2, kA3, s0, idb + 0);
                float s1 = fmaf(-2.f, accA[1], nv.y + niA); INS(kA0, kA1, kA2, kA3, s1, idb + 1);
                float s2 = fmaf(-2.f, accA[2], nv.z + niA); INS(kA0, kA1, kA2, kA3, s2, idb + 2);
                float s3 = fmaf(-2.f, accA[3], nv.w + niA); INS(kA0, kA1, kA2, kA3, s3, idb + 3);
            }
            #undef INS
        }
    }

    // Epilogue: merge 4 lq-stripes per row -> top-4 of 16, decode, write cand.
    __syncthreads();
    float* fbuf = (float*)jbuf;                 // 64 rows x 16 keys = 4 KB
    {
        float* pa = fbuf + (w * 16 + lr) * 16 + lq * 4;
        pa[0] = kA0; pa[1] = kA1; pa[2] = kA2; pa[3] = kA3;
    }
    __syncthreads();
    if (tid < 64) {
        const float* pr = fbuf + tid * 16;
        float m0 = INF, m1 = INF, m2 = INF, m3 = INF;
        #pragma unroll
        for (int q2 = 0; q2 < 16; ++q2) {
            float kf = pr[q2];
            float n0 = fminf(m0, kf);
            float n1 = __builtin_amdgcn_fmed3f(m0, m1, kf);
            float n2 = __builtin_amdgcn_fmed3f(m1, m2, kf);
            float n3 = __builtin_amdgcn_fmed3f(m2, m3, kf);
            m0 = n0; m1 = n1; m2 = n2; m3 = n3;
        }
        ushortx4 cv;
        #define DEC(mf, slot) { unsigned u = __float_as_uint(mf) & 1023u;            \
            cv[slot] = (ushort)(jBase + (((u >> 2) & 63u) << 4) + ((u >> 8) << 2) + (u & 3)); }
        DEC(m0, 0); DEC(m1, 1); DEC(m2, 2); DEC(m3, 3);
        #undef DEC
        int row = b * T_ + i0 + tid;
        *(ushortx4*)(cand + (size_t)row * 16 + h * 4) = cv;
    }
}

// ---------------------------------------------------------------------------
// Refine kernel (verified R18): conv phases 1a-1c, writes per-tile top-3 to
// global jsel (384 B/block). 1024 blocks, 4/CU.
// ---------------------------------------------------------------------------
__global__ __launch_bounds__(256, 4) void refine_kernel(const float* __restrict__ ws,
                                                        float* __restrict__ wsw) {
    const float*  xT   = ws + XT_OFF;
    const float*  nsq  = ws + NSQ_OFF;
    const ushort* cand = (const ushort*)(ws + CAND_OFF);
    int* jsel_g = (int*)(wsw + JSEL_OFF);

    __shared__ float sref[32 * 17];
    __shared__ int   jref[32 * 17];
    __shared__ float q_s[32 * 68];
    __shared__ int   jsel3[32 * 3];

    int bid = blockIdx.x;
    int bb  = (bid & 7) + 8 * (bid >> 9);
    int i0  = ((bid >> 3) & 63) * 32;
    int tid = threadIdx.x;
    int w = tid >> 6, l = tid & 63;
    int bT = bb * T_;

    {
        int row = tid >> 3;
        int c8  = tid & 7;
        const float4* src = (const float4*)(xT + (size_t)(bT + i0 + row) * 64 + c8 * 8);
        float4 v0 = src[0], v1 = src[1];
        *(float4*)(q_s + row * 68 + c8 * 8)     = v0;
        *(float4*)(q_s + row * 68 + c8 * 8 + 4) = v1;
    }

    const float INF = __builtin_inff();
    int cd  = l >> 2;
    int c16 = l & 3;
    int rbase = i0 + w * 8;
    int jtA[8];
    #pragma unroll
    for (int rr = 0; rr < 8; ++rr)
        jtA[rr] = cand[(size_t)(bT + rbase + rr) * 16 + cd];
    __builtin_amdgcn_sched_barrier(0);
    float nsqj[8];
    #pragma unroll
    for (int rr = 0; rr < 8; ++rr)
        nsqj[rr] = nsq[bT + jtA[rr]];

    #pragma unroll
    for (int rp = 0; rp < 2; ++rp) {
        float4 bv0[4], bv1[4], bv2[4], bv3[4];
        #pragma unroll
        for (int r4 = 0; r4 < 4; ++r4) {
            const float4* bp = (const float4*)(xT + (size_t)(bT + jtA[rp * 4 + r4]) * 64 + c16 * 16);
            bv0[r4] = bp[0]; bv1[r4] = bp[1]; bv2[r4] = bp[2]; bv3[r4] = bp[3];
        }
        __builtin_amdgcn_sched_barrier(0);
        #pragma unroll
        for (int r4 = 0; r4 < 4; ++r4) {
            int rl = w * 8 + rp * 4 + r4;
            int jt = jtA[rp * 4 + r4];
            const float4* ap = (const float4*)(q_s + rl * 68 + c16 * 16);
            float4 a0 = ap[0], a1 = ap[1], a2 = ap[2], a3 = ap[3];
            float4 b0 = bv0[r4], b1 = bv1[r4], b2 = bv2[r4], b3 = bv3[r4];
            float p0 = fmaf(b0.w, a0.w, fmaf(b0.z, a0.z, fmaf(b0.y, a0.y, b0.x * a0.x)));
            float p1 = fmaf(b1.w, a1.w, fmaf(b1.z, a1.z, fmaf(b1.y, a1.y, b1.x * a1.x)));
            float p2 = fmaf(b2.w, a2.w, fmaf(b2.z, a2.z, fmaf(b2.y, a2.y, b2.x * a2.x)));
            float p3 = fmaf(b3.w, a3.w, fmaf(b3.z, a3.z, fmaf(b3.y, a3.y, b3.x * a3.x)));
            float p = (p0 + p1) + (p2 + p3);
            p += __shfl_xor(p, 1, 64);
            p += __shfl_xor(p, 2, 64);
            float s = nsqj[rp * 4 + r4] - 2.f * p;
            if (c16 == 0) { sref[rl * 17 + cd] = s; jref[rl * 17 + cd] = jt; }
        }
    }
    __syncthreads();

    if (tid < 32) {
        const float* sp = sref + tid * 17;
        const int*   jp = jref + tid * 17;
        float D0 = INF, D1 = INF, D2 = INF;
        int   I0 = 0x7FFFFFFF, I1 = 0x7FFFFFFF, I2 = 0x7FFFFFFF;
        #pragma unroll
        for (int t = 0; t < 16; ++t) {
            float s  = sp[t];
            int   jt = jp[t];
            bool lt2 = (s < D2) || (s == D2 && jt < I2);
            bool lt1 = (s < D1) || (s == D1 && jt < I1);
            bool lt0 = (s < D0) || (s == D0 && jt < I0);
            float nD2 = lt1 ? D1 : (lt2 ? s : D2); int nI2 = lt1 ? I1 : (lt2 ? jt : I2);
            float nD1 = lt0 ? D0 : (lt1 ? s : D1); int nI1 = lt0 ? I0 : (lt1 ? jt : I1);
            D2 = nD2; I2 = nI2; D1 = nD1; I1 = nI1;
            D0 = lt0 ? s : D0; I0 = lt0 ? jt : I0;
        }
        jsel3[tid * 3 + 0] = I0; jsel3[tid * 3 + 1] = I1; jsel3[tid * 3 + 2] = I2;
    }
    __syncthreads();
    if (tid < 96) jsel_g[(size_t)bid * 96 + tid] = jsel3[tid];
}

// ---------------------------------------------------------------------------
// Conv kernel with Wt staged in LDS (verified R18). 1024 blocks, 2/CU.
// ---------------------------------------------------------------------------
__global__ __launch_bounds__(256, 2) void conv_w_kernel(const float* __restrict__ ws,
                                                        const float* __restrict__ bias,
                                                        float* __restrict__ out) {
    const float*  xT   = ws + XT_OFF;
    const float*  Wt   = ws + WT_OFF;
    const int* jsel_g  = (const int*)(ws + JSEL_OFF);

    __shared__ __align__(16) float wt_s[192 * 64];   // 48 KB
    __shared__ float g_s[192 * 32];                  // 24 KB

    int bid = blockIdx.x;
    int bb  = (bid & 7) + 8 * (bid >> 9);
    int i0  = ((bid >> 3) & 63) * 32;
    int tid = threadIdx.x;
    int bT = bb * T_;

    // Stage Wt -> LDS: 12 rounds x 256 threads x 16 B (linear, coalesced).
    #pragma unroll
    for (int r = 0; r < 12; ++r) {
        const float* gp = Wt + (r * 256 + tid) * 4;
        __builtin_amdgcn_global_load_lds(
            (const __attribute__((address_space(1))) void*)gp,
            (__attribute__((address_space(3))) void*)(wt_s + (r * 256 + tid) * 4),
            16, 0, 0);
    }

    // Phase 2 gather (independent of Wt; overlaps the DMA latency).
    if (tid < 192) {
        int k    = tid >> 6;
        int r6   = tid & 63;
        int ip   = r6 >> 1;
        int half = r6 & 1;
        int j = jsel_g[(size_t)bid * 96 + ip * 3 + k];
        const float4* src = (const float4*)(xT + (size_t)(bT + j) * 64 + half * 32);
        #pragma unroll
        for (int q = 0; q < 8; ++q) {
            float4 v = src[q];
            int mm = k * 64 + (half * 8 + q) * 4;
            g_s[(mm + 0) * 32 + ip] = v.x;
            g_s[(mm + 1) * 32 + ip] = v.y;
            g_s[(mm + 2) * 32 + ip] = v.z;
            g_s[(mm + 3) * 32 + ip] = v.w;
        }
    }
    __syncthreads();   // drains Wt DMA (vmcnt) + g_s writes (lgkmcnt)

    // Phase 3: conv from LDS. Per-(o,i) fmaf chain identical to R6/R15.
    int oq = tid >> 4;
    int iq = tid & 15;
    float a0x = 0.f, a0y = 0.f, a1x = 0.f, a1y = 0.f;
    float a2x = 0.f, a2y = 0.f, a3x = 0.f, a3y = 0.f;
    #pragma unroll 4
    for (int mm = 0; mm < 192; ++mm) {
        float4 wv = *(const float4*)(wt_s + mm * 64 + oq * 4);
        float2 gv = *(const float2*)(g_s + mm * 32 + iq * 2);
        a0x = fmaf(wv.x, gv.x, a0x); a0y = fmaf(wv.x, gv.y, a0y);
        a1x = fmaf(wv.y, gv.x, a1x); a1y = fmaf(wv.y, gv.y, a1y);
        a2x = fmaf(wv.z, gv.x, a2x); a2y = fmaf(wv.z, gv.y, a2y);
        a3x = fmaf(wv.w, gv.x, a3x); a3y = fmaf(wv.w, gv.y, a3y);
    }
    int o0 = oq * 4;
    float b0 = bias[o0], b1 = bias[o0 + 1], b2 = bias[o0 + 2], b3 = bias[o0 + 3];
    float2 r0; r0.x = a0x + b0; r0.y = a0y + b0;
    float2 r1; r1.x = a1x + b1; r1.y = a1y + b1;
    float2 r2; r2.x = a2x + b2; r2.y = a2y + b2;
    float2 r3; r3.x = a3x + b3; r3.y = a3y + b3;
    size_t ob = (size_t)(bb * O_ + o0) * T_ + i0 + iq * 2;
    *(float2*)(out + ob)          = r0;
    *(float2*)(out + ob + T_)     = r1;
    *(float2*)(out + ob + 2 * T_) = r2;
    *(float2*)(out + ob + 3 * T_) = r3;
}

// ---------------------------------------------------------------------------
extern "C" void kernel_launch(void* const* d_in, const int* in_sizes, int n_in,
                              void* d_out, int out_size, void* d_ws, size_t ws_size,
                              hipStream_t stream) {
    const float* x    = (const float*)d_in[0];
    const float* W    = (const float*)d_in[1];
    const float* bias = (const float*)d_in[2];
    float* out = (float*)d_out;
    float* ws  = (float*)d_ws;
    // requires ~18.5 MB workspace

    prep_kernel<<<B_ * (T_ / 64) + 48, 256, 0, stream>>>(x, W, ws);
    knn_mfma_kernel<<<2048, 256, 0, stream>>>(
        (const ushort*)(ws + XS_OFF), ws + NSQ_OFF, (ushort*)(ws + CAND_OFF));
    refine_kernel<<<B_ * 64, 256, 0, stream>>>(ws, ws);
    conv_w_kernel<<<B_ * 64, 256, 0, stream>>>(ws, bias, out);
}